// Round 3
// baseline (13.267 us; speedup 1.0000x reference)
//
#include <hip/hip_runtime.h>
#include <math.h>

// ReliabLoss — analytic simplification (verified R0/R1, absmax 0.0):
//   P = sqrt(Dm)*W*sqrt(Dm) is ELEMENTWISE -> P = diag(d)  (W[i][i]=1)
//   A = 0.5*(I - 0.5*diag(d)) is diagonal -> Fm = phi / A_ii
//   U = Fm / Fm.rowsum = phi / (TAO + sum(labels_row))   (A_ii cancels exactly)
// => outputs depend only on preds (256x81) and labels (256x80). images unused.
//
// R2: single-kernel fusion. R1's 11.6 us was two ~5.8 us graph nodes (dispatch
// overhead dominated; live data is only 165 KB). One block x 1024 threads
// (16 waves), 4 threads per row, 20 classes each (stride-4 interleave ->
// coalesced). exp values stashed in registers (fully unrolled, static index),
// labels as a 20-bit mask. Quarter shfl-reduce for row sums, wave butterfly +
// LDS for the global sums. No atomics (ws is 0xAA-poisoned between the
// correctness call and timed replays, so no cross-call counter is trustable).

constexpr int NC  = 80;    // nclass
constexpr int BS  = 256;   // batch
constexpr int TPB = 1024;  // 16 waves; 4 threads per row
constexpr float TAO_C = 0.2f;
constexpr float EPS_C = 1e-5f;

__global__ __launch_bounds__(TPB, 4)
void reliab_fused_kernel(const float* __restrict__ preds,
                         const float* __restrict__ labels,
                         float* __restrict__ out) {
    const int t   = threadIdx.x;
    const int row = t >> 2;        // 0..255
    const int q   = t & 3;         // quarter within row
    const float* pr = preds  + (size_t)row * (NC + 1);
    const float* lb = labels + (size_t)row * NC;

    // ---- pass 1: load labels + preds, stash exps in regs, labels as bitmask ----
    float e[20];
    unsigned mask = 0u;
    float s_raw = 0.0f;   // this thread's label-sum partial (for global pos count)
    float sum_t = 0.0f;   // this thread's softmax-denominator partial
    #pragma unroll
    for (int k = 0; k < 20; ++k) {
        const int j = q + 4 * k;                 // class index 0..79
        const float lv = lb[j];
        s_raw += lv;
        mask |= (lv == 1.0f ? 1u : 0u) << k;
        e[k] = expf(pr[1 + j]);
        sum_t += e[k];
    }
    const float e0 = expf(pr[0]);                // broadcast load, cheap redundant exp
    if (q == 0) sum_t += e0;

    // ---- per-row reduce across the 4 quarter-lanes (adjacent lanes, same wave) ----
    float s = s_raw, sum = sum_t;
    s   += __shfl_xor(s, 1);    s   += __shfl_xor(s, 2);
    sum += __shfl_xor(sum, 1);  sum += __shfl_xor(sum, 2);

    const float inv_sum = 1.0f / sum;
    const float p0 = e0 * inv_sum;

    // ---- per-row constants from the analytic solve collapse ----
    const float denom = TAO_C + s;               // phi row sum
    const float r     = s / ((float)NC - s);
    const float u1    = 1.0f / denom;
    const float logu1 = logf(u1);

    float kl = 0.0f, rel = 0.0f, irr = 0.0f;
    if (q == 0) {                                // U[:,0] column term, once per row
        const float u0 = TAO_C / denom;
        kl += u0 * (logf(u0) - logf(p0 + EPS_C));
    }

    // ---- pass 2: per-class terms from stashed registers ----
    #pragma unroll
    for (int k = 0; k < 20; ++k) {
        const float pj = e[k] * inv_sum;
        if ((mask >> k) & 1u) {                  // label == 1
            kl  += u1 * (logu1 - logf(pj + EPS_C));
            rel += fmaxf(p0 - pj, 0.0f);
        } else {                                 // label == 0
            irr += fmaxf(r * (pj - p0), 0.0f);
        }
    }

    // ---- full-wave butterfly on (kl, rel, irr, s_raw) ----
    #pragma unroll
    for (int off = 32; off; off >>= 1) {
        kl    += __shfl_xor(kl, off);
        rel   += __shfl_xor(rel, off);
        irr   += __shfl_xor(irr, off);
        s_raw += __shfl_xor(s_raw, off);
    }

    // ---- cross-wave reduce via LDS (16 waves) ----
    __shared__ float4 sm[TPB / 64];
    const int wid = t >> 6;
    if ((t & 63) == 0) sm[wid] = make_float4(kl, rel, irr, s_raw);
    __syncthreads();
    if (t < 16) {
        float4 v = sm[t];
        #pragma unroll
        for (int off = 8; off; off >>= 1) {
            v.x += __shfl_xor(v.x, off);
            v.y += __shfl_xor(v.y, off);
            v.z += __shfl_xor(v.z, off);
            v.w += __shfl_xor(v.w, off);
        }
        if (t == 0) {
            const float pos_cnt = v.w;
            const float neg_cnt = (float)(BS * NC) - pos_cnt;
            out[0] = v.x / (float)BS;
            out[1] = (v.y / pos_cnt + v.z / neg_cnt) * (float)BS;
        }
    }
}

extern "C" void kernel_launch(void* const* d_in, const int* in_sizes, int n_in,
                              void* d_out, int out_size, void* d_ws, size_t ws_size,
                              hipStream_t stream) {
    // d_in[0] = images (unused — mathematically dead, see header comment)
    const float* preds  = (const float*)d_in[1];
    const float* labels = (const float*)d_in[2];
    float* out = (float*)d_out;

    reliab_fused_kernel<<<1, TPB, 0, stream>>>(preds, labels, out);
}